// Round 5
// baseline (122.162 us; speedup 1.0000x reference)
//
#include <hip/hip_runtime.h>

// DisjointDense: out[b] = x[b] @ W[sel[b]] + Bw[sel[b]]
// B=4096, D_IN=256, D_OUT=256, N_DISJOINT=64, all fp32.
//
// R5: single fix over R4 — row indices stay in VGPRs (no readfirstlane), so
// x fragment loads compile to global_load_dwordx4 (in-order vmcnt, HW merges
// the 64 identical lane addresses) instead of s_load_dwordx4 (out-of-order
// lgkmcnt, which forced a full drain every 8 k-steps: VALUBusy 8.5%, SGPR=112).
// W stays L2-resident per-XCD via the blockIdx = quad*64+d swizzle (FETCH 12MB).

#define NBLK 64
#define BCAP 1024
#define CPAD 16   // one counter per 64B cache line

__global__ __launch_bounds__(256) void dd_bucketize(
    const float* __restrict__ onehot,   // [4096, 64]
    int* __restrict__ counts,           // [64*CPAD], zeroed
    int* __restrict__ buckets)          // [64, BCAP]
{
    __shared__ int rowd[256];
    __shared__ int lhist[NBLK];
    __shared__ int lbase[NBLK];
    const int t = threadIdx.x;
    const int w = t >> 6;
    const int lane = t & 63;
    if (t < NBLK) lhist[t] = 0;

    const int row0 = blockIdx.x * 256 + w * 64;
#pragma unroll 8
    for (int i = 0; i < 64; ++i) {
        const float v = onehot[(size_t)(row0 + i) * NBLK + lane];  // coalesced 256B
        const unsigned long long m = __ballot(v > 0.5f);
        const int d = (int)__ffsll(m) - 1;
        if (lane == 0) rowd[w * 64 + i] = d;
    }
    __syncthreads();

    const int d = rowd[t];
    const int slot = atomicAdd(&lhist[d], 1);      // LDS atomic
    __syncthreads();
    if (t < NBLK) lbase[t] = atomicAdd(&counts[t * CPAD], lhist[t]);
    __syncthreads();
    buckets[d * BCAP + lbase[d] + slot] = blockIdx.x * 256 + t;
}

__global__ __launch_bounds__(256, 4) void dd_compute(
    const float* __restrict__ x,        // [4096, 256]
    const float* __restrict__ W,        // [64, 256, 256]  (d, k, col)
    const float* __restrict__ Bw,       // [64, 256]
    const int* __restrict__ counts,     // [64*CPAD]
    const int* __restrict__ buckets,    // [64, BCAP]
    float* __restrict__ out)            // [4096, 256]
{
    const int t    = threadIdx.x;
    const int lane = t & 63;
    const int ct   = t >> 6;                   // wave = col-group
    const int d    = blockIdx.x & 63;          // same-d blocks == d (mod 8) -> one XCD
    const int quad = blockIdx.x >> 6;          // 0..15
    const int c    = ct * 64 + lane;

    const int cnt = counts[d * CPAD];
    const float* Wd  = W + ((size_t)d << 16) + c;   // W[d][k][c], k-stride 256
    const float bias = Bw[d * 256 + c];

    for (int base = quad * 4; base < cnt; base += 64) {
        int  rid[4];
        bool valid[4];
        const float* xr[4];
#pragma unroll
        for (int j = 0; j < 4; ++j) {
            const int idx = base + j;
            valid[j] = (idx < cnt);
            // per-lane load (all lanes same address -> 1 merged request);
            // index stays in a VGPR so x loads below stay on the vmcnt queue.
            rid[j] = buckets[d * BCAP + (valid[j] ? idx : cnt - 1)];
            xr[j]  = x + ((size_t)rid[j] << 8);
        }

        float acc[4];
#pragma unroll
        for (int j = 0; j < 4; ++j) acc[j] = bias;

        float  wa[8], wb[8];
        float4 xa[4][2], xb[4][2];
#pragma unroll
        for (int i = 0; i < 8; ++i) wa[i] = Wd[i * 256];
#pragma unroll
        for (int j = 0; j < 4; ++j) {
            xa[j][0] = *(const float4*)(xr[j] + 0);   // global_load_dwordx4 broadcast
            xa[j][1] = *(const float4*)(xr[j] + 4);
        }

#pragma unroll 1
        for (int k0 = 0; k0 < 256; k0 += 16) {
            // prefetch half B (k0+8) while computing half A (k0)
#pragma unroll
            for (int i = 0; i < 8; ++i) wb[i] = Wd[((k0 + 8 + i) & 255) * 256];
#pragma unroll
            for (int j = 0; j < 4; ++j) {
                xb[j][0] = *(const float4*)(xr[j] + ((k0 + 8)  & 255));
                xb[j][1] = *(const float4*)(xr[j] + ((k0 + 12) & 255));
            }
#pragma unroll
            for (int j = 0; j < 4; ++j) {
                acc[j] = fmaf(xa[j][0].x, wa[0], acc[j]);
                acc[j] = fmaf(xa[j][0].y, wa[1], acc[j]);
                acc[j] = fmaf(xa[j][0].z, wa[2], acc[j]);
                acc[j] = fmaf(xa[j][0].w, wa[3], acc[j]);
                acc[j] = fmaf(xa[j][1].x, wa[4], acc[j]);
                acc[j] = fmaf(xa[j][1].y, wa[5], acc[j]);
                acc[j] = fmaf(xa[j][1].z, wa[6], acc[j]);
                acc[j] = fmaf(xa[j][1].w, wa[7], acc[j]);
            }
            // prefetch half A' (k0+16) while computing half B (k0+8)
#pragma unroll
            for (int i = 0; i < 8; ++i) wa[i] = Wd[((k0 + 16 + i) & 255) * 256];
#pragma unroll
            for (int j = 0; j < 4; ++j) {
                xa[j][0] = *(const float4*)(xr[j] + ((k0 + 16) & 255));
                xa[j][1] = *(const float4*)(xr[j] + ((k0 + 20) & 255));
            }
#pragma unroll
            for (int j = 0; j < 4; ++j) {
                acc[j] = fmaf(xb[j][0].x, wb[0], acc[j]);
                acc[j] = fmaf(xb[j][0].y, wb[1], acc[j]);
                acc[j] = fmaf(xb[j][0].z, wb[2], acc[j]);
                acc[j] = fmaf(xb[j][0].w, wb[3], acc[j]);
                acc[j] = fmaf(xb[j][1].x, wb[4], acc[j]);
                acc[j] = fmaf(xb[j][1].y, wb[5], acc[j]);
                acc[j] = fmaf(xb[j][1].z, wb[6], acc[j]);
                acc[j] = fmaf(xb[j][1].w, wb[7], acc[j]);
            }
        }

#pragma unroll
        for (int j = 0; j < 4; ++j) {
            if (valid[j]) out[((size_t)rid[j] << 8) + c] = acc[j];
        }
    }
}

extern "C" void kernel_launch(void* const* d_in, const int* in_sizes, int n_in,
                              void* d_out, int out_size, void* d_ws, size_t ws_size,
                              hipStream_t stream) {
    const float* x      = (const float*)d_in[0];   // [4096, 256]
    const float* onehot = (const float*)d_in[1];   // [4096, 64]
    const float* W      = (const float*)d_in[2];   // [64, 256, 256]
    const float* Bw     = (const float*)d_in[3];   // [64, 256]
    float* out = (float*)d_out;                    // [4096, 256]

    int* counts  = (int*)d_ws;                             // 64*CPAD ints (4 KB)
    int* buckets = (int*)((char*)d_ws + NBLK * CPAD * 4);  // 64*BCAP ints (256 KB)

    hipMemsetAsync(counts, 0, NBLK * CPAD * sizeof(int), stream);
    dd_bucketize<<<16, 256, 0, stream>>>(onehot, counts, buckets);
    dd_compute<<<NBLK * 16, 256, 0, stream>>>(x, W, Bw, counts, buckets, out);
}

// Round 6
// 97.650 us; speedup vs baseline: 1.2510x; 1.2510x over previous
//
#include <hip/hip_runtime.h>

// DisjointDense: out[b] = x[b] @ W[sel[b]] + Bw[sel[b]]
// B=4096, D_IN=256, D_OUT=256, N_DISJOINT=64, all fp32.
//
// R6: bf16 MFMA (16x16x32) with on-the-fly fp32->bf16 conversion.
// Rationale: fp32-VALU designs are structurally latency-bound here (small
// tiles needed for occupancy give only 4-row W reuse; R4/R5 sat at 8% VALU).
// One MFMA gives 16x16 reuse per instruction at 4096-wave parallelism.
// Tolerance 0.108 >> bf16 error (~5e-3). fp32 accumulate.
//
// Layouts (HW-verified per guide m89/m91/m120):
//   A-frag: lane holds A[m=lane&15][k=(lane>>4)*8+j], j=0..7
//   B-frag: lane holds B[k=(lane>>4)*8+j][n=lane&15]
//   C/D:    col=lane&15, row=(lane>>4)*4+reg

#define NBLK 64
#define BCAP 1024
#define CPAD 16

typedef __attribute__((ext_vector_type(8))) short bf16x8;
typedef __attribute__((ext_vector_type(4))) float f32x4;

__device__ __forceinline__ unsigned short f2bf(float f) {
    unsigned u = __float_as_uint(f);
    u += 0x7FFFu + ((u >> 16) & 1u);       // round-to-nearest-even
    return (unsigned short)(u >> 16);
}

__global__ __launch_bounds__(256) void dd_bucketize(
    const float* __restrict__ onehot,   // [4096, 64]
    int* __restrict__ counts,           // [64*CPAD], zeroed
    int* __restrict__ buckets)          // [64, BCAP]
{
    __shared__ int rowd[256];
    __shared__ int lhist[NBLK];
    __shared__ int lbase[NBLK];
    const int t = threadIdx.x;
    const int w = t >> 6;
    const int lane = t & 63;
    if (t < NBLK) lhist[t] = 0;

    const int row0 = blockIdx.x * 256 + w * 64;
#pragma unroll 8
    for (int i = 0; i < 64; ++i) {
        const float v = onehot[(size_t)(row0 + i) * NBLK + lane];  // coalesced 256B
        const unsigned long long m = __ballot(v > 0.5f);
        const int d = (int)__ffsll(m) - 1;
        if (lane == 0) rowd[w * 64 + i] = d;
    }
    __syncthreads();

    const int d = rowd[t];
    const int slot = atomicAdd(&lhist[d], 1);
    __syncthreads();
    if (t < NBLK) lbase[t] = atomicAdd(&counts[t * CPAD], lhist[t]);
    __syncthreads();
    buckets[d * BCAP + lbase[d] + slot] = blockIdx.x * 256 + t;
}

// 512 blocks: [q:3][d:6] with d = blockIdx&63 (XCD affinity), q = rt*4+ct.
// Block tile: 32 bucket-rows x 64 cols, K=256. 4 waves = 4 col-slices of 16.
__global__ __launch_bounds__(256, 2) void dd_compute(
    const float* __restrict__ x,        // [4096, 256]
    const float* __restrict__ W,        // [64, 256, 256]  (d, k, col)
    const float* __restrict__ Bw,       // [64, 256]
    const int* __restrict__ counts,     // [64*CPAD]
    const int* __restrict__ buckets,    // [64, BCAP]
    float* __restrict__ out)            // [4096, 256]
{
    __shared__ unsigned short xbf[32][264];   // 32 rows x 256 k (bf16), +8 pad shorts
    __shared__ int lrid[32];

    const int t    = threadIdx.x;
    const int lane = t & 63;
    const int w    = t >> 6;                  // wave = col-slice
    const int d    = blockIdx.x & 63;
    const int q    = blockIdx.x >> 6;         // 0..7
    const int rt   = q >> 2;                  // 0..1
    const int ct   = q & 3;                   // 0..3
    const int cw   = ct * 64 + w * 16;        // wave's col base
    const int m    = lane & 15;
    const int qd   = lane >> 4;               // quad

    const int cnt = counts[d * CPAD];
    const float* Wd = W + ((size_t)d << 16);
    const float bias = Bw[d * 256 + cw + m];

    for (int base = rt * 32; base < cnt; base += 64) {
        // ---- stage rids + 32 x-rows as bf16 into LDS ----
        {
            const int row = t >> 3;            // 0..31
            const int kc  = (t & 7) * 32;      // 0..224
            const int idx = base + row;
            const int r = buckets[d * BCAP + (idx < cnt ? idx : cnt - 1)];
            if ((t & 7) == 0) lrid[row] = r;
            const float* xp = x + ((size_t)r << 8) + kc;
#pragma unroll
            for (int i = 0; i < 8; ++i) {
                const float4 v = *(const float4*)(xp + i * 4);
                ushort4 b;
                b.x = f2bf(v.x); b.y = f2bf(v.y); b.z = f2bf(v.z); b.w = f2bf(v.w);
                *(ushort4*)&xbf[row][kc + i * 4] = b;
            }
        }
        __syncthreads();

        // ---- B fragments: 8 k-blocks, fp32 W -> bf16 (64 independent loads) ----
        bf16x8 bfrag[8];
#pragma unroll
        for (int kb = 0; kb < 8; ++kb) {
            const float* wp = Wd + (size_t)(kb * 32 + qd * 8) * 256 + (cw + m);
#pragma unroll
            for (int j = 0; j < 8; ++j)
                bfrag[kb][j] = (short)f2bf(wp[j * 256]);
        }

        // ---- two 16-row subtiles, 8 MFMAs each ----
        f32x4 acc0 = {bias, bias, bias, bias};
        f32x4 acc1 = {bias, bias, bias, bias};
        const int koff = qd * 8;
#pragma unroll
        for (int kb = 0; kb < 8; ++kb) {
            bf16x8 a = *(const bf16x8*)&xbf[m][kb * 32 + koff];
            acc0 = __builtin_amdgcn_mfma_f32_16x16x32_bf16(a, bfrag[kb], acc0, 0, 0, 0);
        }
#pragma unroll
        for (int kb = 0; kb < 8; ++kb) {
            bf16x8 a = *(const bf16x8*)&xbf[16 + m][kb * 32 + koff];
            acc1 = __builtin_amdgcn_mfma_f32_16x16x32_bf16(a, bfrag[kb], acc1, 0, 0, 0);
        }

        // ---- store (C/D: row = qd*4+reg, col = m), mask padded rows ----
#pragma unroll
        for (int reg = 0; reg < 4; ++reg) {
            const int rl0 = qd * 4 + reg;
            if (base + rl0 < cnt)
                out[(size_t)lrid[rl0] * 256 + cw + m] = acc0[reg];
            const int rl1 = 16 + qd * 4 + reg;
            if (base + rl1 < cnt)
                out[(size_t)lrid[rl1] * 256 + cw + m] = acc1[reg];
        }
        __syncthreads();   // xbf/lrid reused next iteration
    }
}

extern "C" void kernel_launch(void* const* d_in, const int* in_sizes, int n_in,
                              void* d_out, int out_size, void* d_ws, size_t ws_size,
                              hipStream_t stream) {
    const float* x      = (const float*)d_in[0];   // [4096, 256]
    const float* onehot = (const float*)d_in[1];   // [4096, 64]
    const float* W      = (const float*)d_in[2];   // [64, 256, 256]
    const float* Bw     = (const float*)d_in[3];   // [64, 256]
    float* out = (float*)d_out;                    // [4096, 256]

    int* counts  = (int*)d_ws;                             // 64*CPAD ints (4 KB)
    int* buckets = (int*)((char*)d_ws + NBLK * CPAD * 4);  // 64*BCAP ints (256 KB)

    hipMemsetAsync(counts, 0, NBLK * CPAD * sizeof(int), stream);
    dd_bucketize<<<16, 256, 0, stream>>>(onehot, counts, buckets);
    dd_compute<<<512, 256, 0, stream>>>(x, W, Bw, counts, buckets, out);
}

// Round 7
// 92.498 us; speedup vs baseline: 1.3207x; 1.0557x over previous
//
#include <hip/hip_runtime.h>

// DisjointDense: out[b] = x[b] @ W[sel[b]] + Bw[sel[b]]
// B=4096, D_IN=256, D_OUT=256, N_DISJOINT=64, all fp32.
//
// R7 (over R6's MFMA kernel):
//  - dd_swizzle: W fp32 -> bf16 pre-packed in exact MFMA B-fragment order
//    (chunk = ((d*16+c16)*8+kb), 64 lanes x 16B). Compute loads B-frags as
//    8 contiguous dwordx4 per wave, hoisted OUT of the row loop (R6 reloaded
//    64 strided scalars + cvts every iteration -- the dominant chain).
//    Also zeroes counts (memset dispatch eliminated).
//  - x staging: one row per wave-pass, 64 lanes x float4 = 1KB contiguous.
//  - bucketize: 32 blocks (was 16) to halve serialized HBM batch depth.

#define NBLK 64
#define BCAP 1024
#define CPAD 16

typedef __attribute__((ext_vector_type(8))) short bf16x8;
typedef __attribute__((ext_vector_type(4))) float f32x4;

__device__ __forceinline__ unsigned short f2bf(float f) {
    unsigned u = __float_as_uint(f);
    u += 0x7FFFu + ((u >> 16) & 1u);       // round-to-nearest-even
    return (unsigned short)(u >> 16);
}

// grid 2048: d = blockIdx&63 (XCD affinity), task = (blockIdx>>6)*4 + wave.
// task = c16*8 + kb. Lane layout identical to the consumer's B-fragment.
__global__ __launch_bounds__(256) void dd_swizzle(
    const float* __restrict__ W,          // [64, 256, 256]
    unsigned short* __restrict__ Wb,      // [64*16*8 chunks][64 lanes][8 bf16]
    int* __restrict__ counts)             // [64*CPAD] -- zeroed here
{
    if (blockIdx.x == 0 && threadIdx.x < NBLK) counts[threadIdx.x * CPAD] = 0;
    const int t = threadIdx.x, lane = t & 63, w = t >> 6;
    const int d    = blockIdx.x & 63;
    const int task = (blockIdx.x >> 6) * 4 + w;   // 0..127
    const int c16  = task >> 3;                   // 16-col tile
    const int kb   = task & 7;                    // 32-k block
    const int m = lane & 15, qd = lane >> 4;

    const float* wp = W + ((size_t)d << 16)
                        + (size_t)(kb * 32 + qd * 8) * 256 + c16 * 16 + m;
    bf16x8 frag;
#pragma unroll
    for (int j = 0; j < 8; ++j) frag[j] = (short)f2bf(wp[j * 256]);

    unsigned short* dst = Wb + ((size_t)((d * 16 + c16) * 8 + kb) * 64 + lane) * 8;
    *(bf16x8*)dst = frag;                          // coalesced 1KB per wave
}

__global__ __launch_bounds__(256) void dd_bucketize(
    const float* __restrict__ onehot,   // [4096, 64]
    int* __restrict__ counts,           // [64*CPAD], zeroed by dd_swizzle
    int* __restrict__ buckets)          // [64, BCAP]
{
    __shared__ int rowd[128];
    __shared__ int lhist[NBLK];
    __shared__ int lbase[NBLK];
    const int t = threadIdx.x;
    const int w = t >> 6;
    const int lane = t & 63;
    if (t < NBLK) lhist[t] = 0;

    const int row0 = blockIdx.x * 128 + w * 32;   // 32 blocks x 128 rows
#pragma unroll 8
    for (int i = 0; i < 32; ++i) {
        const float v = onehot[(size_t)(row0 + i) * NBLK + lane];  // coalesced 256B
        const unsigned long long mm = __ballot(v > 0.5f);
        const int d = (int)__ffsll(mm) - 1;
        if (lane == 0) rowd[w * 32 + i] = d;
    }
    __syncthreads();

    int d = 0, slot = 0;
    if (t < 128) {
        d = rowd[t];
        slot = atomicAdd(&lhist[d], 1);
    }
    __syncthreads();
    if (t < NBLK) lbase[t] = atomicAdd(&counts[t * CPAD], lhist[t]);
    __syncthreads();
    if (t < 128) buckets[d * BCAP + lbase[d] + slot] = blockIdx.x * 128 + t;
}

// 512 blocks: [q:3][d:6], d = blockIdx&63 (XCD affinity), q = rt*4+ct.
// Block tile: 32 bucket-rows x 64 cols. 4 waves = 4 col-slices of 16.
__global__ __launch_bounds__(256) void dd_compute(
    const float* __restrict__ x,              // [4096, 256]
    const unsigned short* __restrict__ Wb,    // pre-swizzled bf16 B-frags
    const float* __restrict__ Bw,             // [64, 256]
    const int* __restrict__ counts,           // [64*CPAD]
    const int* __restrict__ buckets,          // [64, BCAP]
    float* __restrict__ out)                  // [4096, 256]
{
    __shared__ unsigned short xbf[32][264];   // 32 rows x 256 k bf16, +8 pad
    __shared__ int lrid[32];

    const int t    = threadIdx.x;
    const int lane = t & 63;
    const int w    = t >> 6;                  // wave = col-slice
    const int d    = blockIdx.x & 63;
    const int q    = blockIdx.x >> 6;         // 0..7
    const int rt   = q >> 2;
    const int ct   = q & 3;
    const int cw   = ct * 64 + w * 16;        // wave's col base
    const int m    = lane & 15;
    const int qd   = lane >> 4;

    const int cnt = counts[d * CPAD];
    const float bias = Bw[d * 256 + cw + m];

    // loop-invariant B fragments: 8 contiguous 16B loads (chunk c16 = ct*4+w)
    bf16x8 bfrag[8];
    const unsigned short* wbase =
        Wb + ((size_t)(d * 16 + ct * 4 + w) * 8) * 512 + (size_t)lane * 8;
#pragma unroll
    for (int kb = 0; kb < 8; ++kb)
        bfrag[kb] = *(const bf16x8*)(wbase + (size_t)kb * 512);

    for (int base = rt * 32; base < cnt; base += 64) {
        if (t < 32) lrid[t] = buckets[d * BCAP + (base + t < cnt ? base + t : cnt - 1)];
        __syncthreads();

        // stage 32 rows: one row per wave-pass, 64 lanes x float4 = 1KB contiguous
#pragma unroll
        for (int p = 0; p < 8; ++p) {
            const int row = p * 4 + w;
            const int r = lrid[row];
            const float4 v = ((const float4*)(x + ((size_t)r << 8)))[lane];
            ushort4 b;
            b.x = f2bf(v.x); b.y = f2bf(v.y); b.z = f2bf(v.z); b.w = f2bf(v.w);
            *(ushort4*)&xbf[row][lane * 4] = b;
        }
        __syncthreads();

        f32x4 acc0 = {bias, bias, bias, bias};
        f32x4 acc1 = {bias, bias, bias, bias};
        const int koff = qd * 8;
#pragma unroll
        for (int kb = 0; kb < 8; ++kb) {
            bf16x8 a = *(const bf16x8*)&xbf[m][kb * 32 + koff];
            acc0 = __builtin_amdgcn_mfma_f32_16x16x32_bf16(a, bfrag[kb], acc0, 0, 0, 0);
        }
#pragma unroll
        for (int kb = 0; kb < 8; ++kb) {
            bf16x8 a = *(const bf16x8*)&xbf[16 + m][kb * 32 + koff];
            acc1 = __builtin_amdgcn_mfma_f32_16x16x32_bf16(a, bfrag[kb], acc1, 0, 0, 0);
        }

        // C/D: row = qd*4+reg, col = m; mask padded rows
#pragma unroll
        for (int reg = 0; reg < 4; ++reg) {
            const int rl0 = qd * 4 + reg;
            if (base + rl0 < cnt)
                out[(size_t)lrid[rl0] * 256 + cw + m] = acc0[reg];
            const int rl1 = 16 + qd * 4 + reg;
            if (base + rl1 < cnt)
                out[(size_t)lrid[rl1] * 256 + cw + m] = acc1[reg];
        }
        __syncthreads();   // xbf/lrid reused next iteration
    }
}

extern "C" void kernel_launch(void* const* d_in, const int* in_sizes, int n_in,
                              void* d_out, int out_size, void* d_ws, size_t ws_size,
                              hipStream_t stream) {
    const float* x      = (const float*)d_in[0];   // [4096, 256]
    const float* onehot = (const float*)d_in[1];   // [4096, 64]
    const float* W      = (const float*)d_in[2];   // [64, 256, 256]
    const float* Bw     = (const float*)d_in[3];   // [64, 256]
    float* out = (float*)d_out;                    // [4096, 256]

    // d_ws layout: counts 4KB | buckets 256KB | Wb 8MB (16B-aligned)
    int* counts  = (int*)d_ws;
    int* buckets = (int*)((char*)d_ws + NBLK * CPAD * 4);
    unsigned short* Wb = (unsigned short*)((char*)d_ws + NBLK * CPAD * 4 + NBLK * BCAP * 4);

    dd_swizzle<<<2048, 256, 0, stream>>>(W, Wb, counts);
    dd_bucketize<<<32, 256, 0, stream>>>(onehot, counts, buckets);
    dd_compute<<<512, 256, 0, stream>>>(x, Wb, Bw, counts, buckets, out);
}

// Round 8
// 85.893 us; speedup vs baseline: 1.4223x; 1.0769x over previous
//
#include <hip/hip_runtime.h>

// DisjointDense: out[b] = x[b] @ W[sel[b]] + Bw[sel[b]]
// B=4096, D_IN=256, D_OUT=256, N_DISJOINT=64, all fp32.
//
// R8: three dispatches -> memset(4KB) + dd_prep + dd_compute.
//  - dd_prep fuses bucketize with x fp32->bf16 conversion (xb, 2MB in ws).
//  - dd_compute is LDS-free and barrier-free: A-frags are direct 16B bf16
//    gathers from xb (4-wave redundancy hits L1); B-frags built from W fp32
//    once per block (loop-invariant, 64 independent strided loads + cvt);
//    W stays L2-resident via d = blockIdx&63 XCD affinity. Grid 1024 with
//    early-exit on cnt -> ~4 blocks/CU, pure latency overlap.

#define NBLK 64
#define BCAP 1024
#define CPAD 16

typedef __attribute__((ext_vector_type(8))) short bf16x8;
typedef __attribute__((ext_vector_type(4))) float f32x4;

__device__ __forceinline__ unsigned short f2bf(float f) {
    unsigned u = __float_as_uint(f);
    u += 0x7FFFu + ((u >> 16) & 1u);       // round-to-nearest-even
    return (unsigned short)(u >> 16);
}

// 128 blocks x 256 threads; block handles 32 rows: bucketize + x->bf16.
__global__ __launch_bounds__(256) void dd_prep(
    const float* __restrict__ x,        // [4096, 256]
    const float* __restrict__ onehot,   // [4096, 64]
    int* __restrict__ counts,           // [64*CPAD], pre-zeroed
    int* __restrict__ buckets,          // [64, BCAP]
    unsigned short* __restrict__ xb)    // [4096, 256] bf16
{
    __shared__ int rowd[32];
    __shared__ int lhist[NBLK];
    __shared__ int lbase[NBLK];
    const int t = threadIdx.x;
    const int w = t >> 6;
    const int lane = t & 63;
    if (t < NBLK) lhist[t] = 0;

    const int row0 = blockIdx.x * 32;
    // ballots: wave w covers rows w*8 .. w*8+7
#pragma unroll
    for (int i = 0; i < 8; ++i) {
        const int row = row0 + w * 8 + i;
        const float v = onehot[(size_t)row * NBLK + lane];   // coalesced 256B
        const unsigned long long mm = __ballot(v > 0.5f);
        const int d = (int)__ffsll(mm) - 1;
        if (lane == 0) rowd[w * 8 + i] = d;
    }
    // x -> bf16: wave w covers rows w*8 .. w*8+7, 1 float4/lane/row
#pragma unroll
    for (int i = 0; i < 8; ++i) {
        const int row = row0 + w * 8 + i;
        const float4 v = ((const float4*)(x + ((size_t)row << 8)))[lane];
        ushort4 b;
        b.x = f2bf(v.x); b.y = f2bf(v.y); b.z = f2bf(v.z); b.w = f2bf(v.w);
        *(ushort4*)(xb + ((size_t)row << 8) + lane * 4) = b;   // 512B/row contiguous
    }
    __syncthreads();

    int d = 0, slot = 0;
    if (t < 32) {
        d = rowd[t];
        slot = atomicAdd(&lhist[d], 1);        // LDS atomic
    }
    __syncthreads();
    if (t < NBLK && lhist[t] > 0)              // skip zero increments
        lbase[t] = atomicAdd(&counts[t * CPAD], lhist[t]);
    __syncthreads();
    if (t < 32) buckets[d * BCAP + lbase[d] + slot] = row0 + t;
}

// 1024 blocks: [task:4][d:6], d = blockIdx&63 (XCD affinity).
// task = rt*... rt = task>>2 (row tile, base rt*32, stride 128), ct = task&3.
// Block tile: 32 bucket-rows x 64 cols; 4 waves = 4 col-slices of 16.
// No LDS, no barriers.
__global__ __launch_bounds__(256) void dd_compute(
    const unsigned short* __restrict__ xb,    // [4096, 256] bf16
    const float* __restrict__ W,              // [64, 256, 256] (d, k, col)
    const float* __restrict__ Bw,             // [64, 256]
    const int* __restrict__ counts,           // [64*CPAD]
    const int* __restrict__ buckets,          // [64, BCAP]
    float* __restrict__ out)                  // [4096, 256]
{
    const int t    = threadIdx.x;
    const int lane = t & 63;
    const int w    = t >> 6;                  // wave = col-slice
    const int d    = blockIdx.x & 63;
    const int task = blockIdx.x >> 6;         // 0..15
    const int rt   = task >> 2;               // 0..3
    const int ct   = task & 3;                // 0..3
    const int cw   = ct * 64 + w * 16;        // wave's col base
    const int m    = lane & 15;
    const int qd   = lane >> 4;

    const int cnt = counts[d * CPAD];
    if (rt * 32 >= cnt) return;               // early exit before W prologue

    // loop-invariant B fragments straight from fp32 W:
    // lane holds B[k=kb*32+qd*8+j][n=cw+m]
    const float* wb = W + ((size_t)d << 16) + (size_t)(qd * 8) * 256 + (cw + m);
    bf16x8 bfrag[8];
#pragma unroll
    for (int kb = 0; kb < 8; ++kb) {
        const float* wp = wb + (size_t)(kb * 32) * 256;
#pragma unroll
        for (int j = 0; j < 8; ++j)
            bfrag[kb][j] = (short)f2bf(wp[j * 256]);
    }

    const float bias = Bw[d * 256 + cw + m];
    const int* bkt = buckets + d * BCAP;

    for (int base = rt * 32; base < cnt; base += 128) {
        // per-lane row-id gathers (16 distinct addresses each -> 1-2 lines)
        const int i0 = base + m;
        const int i1 = base + 16 + m;
        const int r0 = bkt[i0 < cnt ? i0 : cnt - 1];
        const int r1 = bkt[i1 < cnt ? i1 : cnt - 1];

        // A fragments: direct 16B bf16 loads, rows r0/r1, k = kb*32 + qd*8
        const unsigned short* xp0 = xb + ((size_t)r0 << 8) + qd * 8;
        const unsigned short* xp1 = xb + ((size_t)r1 << 8) + qd * 8;

        f32x4 acc0 = {bias, bias, bias, bias};
        f32x4 acc1 = {bias, bias, bias, bias};
#pragma unroll
        for (int kb = 0; kb < 8; ++kb) {
            bf16x8 a0 = *(const bf16x8*)(xp0 + kb * 32);
            acc0 = __builtin_amdgcn_mfma_f32_16x16x32_bf16(a0, bfrag[kb], acc0, 0, 0, 0);
        }
#pragma unroll
        for (int kb = 0; kb < 8; ++kb) {
            bf16x8 a1 = *(const bf16x8*)(xp1 + kb * 32);
            acc1 = __builtin_amdgcn_mfma_f32_16x16x32_bf16(a1, bfrag[kb], acc1, 0, 0, 0);
        }

        // stores: C/D row = qd*4+reg, col = m; re-gather rids (L1-hot)
#pragma unroll
        for (int reg = 0; reg < 4; ++reg) {
            const int rl0 = base + qd * 4 + reg;
            if (rl0 < cnt) {
                const int rr = bkt[rl0];
                out[((size_t)rr << 8) + cw + m] = acc0[reg];
            }
            const int rl1 = base + 16 + qd * 4 + reg;
            if (rl1 < cnt) {
                const int rr = bkt[rl1];
                out[((size_t)rr << 8) + cw + m] = acc1[reg];
            }
        }
    }
}

extern "C" void kernel_launch(void* const* d_in, const int* in_sizes, int n_in,
                              void* d_out, int out_size, void* d_ws, size_t ws_size,
                              hipStream_t stream) {
    const float* x      = (const float*)d_in[0];   // [4096, 256]
    const float* onehot = (const float*)d_in[1];   // [4096, 64]
    const float* W      = (const float*)d_in[2];   // [64, 256, 256]
    const float* Bw     = (const float*)d_in[3];   // [64, 256]
    float* out = (float*)d_out;                    // [4096, 256]

    // ws layout: counts 4KB | buckets 256KB | xb 2MB
    int* counts  = (int*)d_ws;
    int* buckets = (int*)((char*)d_ws + NBLK * CPAD * 4);
    unsigned short* xb = (unsigned short*)((char*)d_ws + NBLK * CPAD * 4 + NBLK * BCAP * 4);

    hipMemsetAsync(counts, 0, NBLK * CPAD * sizeof(int), stream);
    dd_prep<<<128, 256, 0, stream>>>(x, onehot, counts, buckets, xb);
    dd_compute<<<1024, 256, 0, stream>>>(xb, W, Bw, counts, buckets, out);
}